// Round 1
// baseline (199.831 us; speedup 1.0000x reference)
//
#include <hip/hip_runtime.h>
#include <stdint.h>

#define NEXP 9

typedef float v2f __attribute__((ext_vector_type(2)));

__device__ __forceinline__ v2f ldv2(const float* p) { return *(const v2f*)p; }
__device__ __forceinline__ v2f relu2(v2f a) {
    v2f r; r.x = fmaxf(a.x, 0.f); r.y = fmaxf(a.y, 0.f); return r;
}

__device__ __forceinline__ int expert_of(float fr) {
    const float frs[NEXP] = {1.f, 2.f, 4.f, 8.f, 16.f, 25.f, 36.f, 50.f, 75.f};
    int k = 0;
    float best = fabsf(fr - frs[0]);
#pragma unroll
    for (int e = 1; e < NEXP; ++e) {
        float d = fabsf(fr - frs[e]);
        if (d < best) { best = d; k = e; }
    }
    return k;
}

// ---------------- K1: expert id + histogram ----------------
__global__ __launch_bounds__(256) void k_hist(const float* __restrict__ feat, int n,
                                              int* __restrict__ hist,
                                              uint8_t* __restrict__ karr) {
    __shared__ int lh[NEXP];
    if (threadIdx.x < NEXP) lh[threadIdx.x] = 0;
    __syncthreads();
    int i = blockIdx.x * 256 + threadIdx.x;
    int lane = threadIdx.x & 63;
    int k = -1;
    if (i < n) {
        k = expert_of(feat[(size_t)i * 5]);
        karr[i] = (uint8_t)k;
    }
#pragma unroll
    for (int e = 0; e < NEXP; ++e) {
        unsigned long long mm = __ballot(k == e);
        if (lane == 0 && mm) atomicAdd(&lh[e], __popcll(mm));
    }
    __syncthreads();
    if (threadIdx.x < NEXP) {
        int c = lh[threadIdx.x];
        if (c) atomicAdd(&hist[threadIdx.x], c);
    }
}

// ---------------- K2: W4 rowsums, b4 sums, padded prefix sum ----------------
__global__ __launch_bounds__(1024) void k_prep(const int* __restrict__ hist,
                                               const float* __restrict__ W4,
                                               const float* __restrict__ b4,
                                               int* __restrict__ pad_base,
                                               float* __restrict__ w4s,
                                               float* __restrict__ b4s) {
    int t = threadIdx.x;
    if (t < NEXP * 64) {
        const float* w = W4 + (size_t)t * 64;
        float s = 0.f;
#pragma unroll
        for (int o = 0; o < 64; ++o) s += w[o];
        w4s[t] = s;
    } else if (t >= 576 && t < 576 + NEXP) {
        int e = t - 576;
        const float* bb = b4 + e * 64;
        float s = 0.f;
#pragma unroll
        for (int o = 0; o < 64; ++o) s += bb[o];
        b4s[e] = s;
    } else if (t == 1000) {
        int acc = 0;
        for (int e = 0; e < NEXP; ++e) {
            pad_base[e] = acc;
            acc += (hist[e] + 63) & ~63;
        }
        pad_base[NEXP] = acc;
    }
}

// ---------------- K3: scatter indices into padded expert buckets ----------------
__global__ __launch_bounds__(256) void k_scatter(const uint8_t* __restrict__ karr, int n,
                                                 const int* __restrict__ pad_base,
                                                 int* __restrict__ pos,
                                                 unsigned* __restrict__ idxb) {
    __shared__ int wcnt[4][NEXP];
    __shared__ int bbase[NEXP];
    int i = blockIdx.x * 256 + threadIdx.x;
    int wid = threadIdx.x >> 6, lane = threadIdx.x & 63;
    int k = (i < n) ? (int)karr[i] : -1;
    unsigned long long myMask = 0;
#pragma unroll
    for (int e = 0; e < NEXP; ++e) {
        unsigned long long mm = __ballot(k == e);
        if (lane == 0) wcnt[wid][e] = __popcll(mm);
        if (k == e) myMask = mm;
    }
    __syncthreads();
    if (threadIdx.x < NEXP) {
        int e = threadIdx.x;
        int tot = wcnt[0][e] + wcnt[1][e] + wcnt[2][e] + wcnt[3][e];
        bbase[e] = tot ? atomicAdd(&pos[e], tot) : 0;
    }
    __syncthreads();
    if (k >= 0) {
        int before = 0;
        for (int w = 0; w < wid; ++w) before += wcnt[w][k];
        int rank = __popcll(myMask & ((1ull << lane) - 1ull));
        idxb[pad_base[k] + bbase[k] + before + rank] = (unsigned)i;
    }
}

// ---------------- K4: wave-uniform-expert MLP ----------------
__global__ __launch_bounds__(256) void k_mlp(const float* __restrict__ feat,
                                             const float* __restrict__ W1, const float* __restrict__ b1,
                                             const float* __restrict__ W2, const float* __restrict__ b2,
                                             const float* __restrict__ W3, const float* __restrict__ b3,
                                             const int* __restrict__ hist,
                                             const int* __restrict__ pad_base,
                                             const float* __restrict__ w4s,
                                             const float* __restrict__ b4s,
                                             const unsigned* __restrict__ idxb,
                                             float* __restrict__ out, int n) {
    int g = blockIdx.x * 256 + threadIdx.x;
    int e = 0;
#pragma unroll
    for (int t = 1; t < NEXP; ++t) e += (g >= pad_base[t]);
    int e0 = __builtin_amdgcn_readfirstlane(e);   // waves are expert-uniform by 64-padding
    bool valid = (g - pad_base[e0]) < hist[e0];
    if (!__any(valid)) return;
    unsigned idx = valid ? idxb[g] : 0u;
    const float* f = feat + (size_t)idx * 5;
    float x0 = f[1], x1 = f[2], x2 = f[3], x3 = f[4];

    // layer 1: 4 -> 32
    const float* w1e = W1 + e0 * 128;
    const float* b1e = b1 + e0 * 32;
    v2f h1[16];
#pragma unroll
    for (int j = 0; j < 16; ++j) {
        v2f a = ldv2(b1e + 2 * j);
        a += x0 * ldv2(w1e + 2 * j);
        a += x1 * ldv2(w1e + 32 + 2 * j);
        a += x2 * ldv2(w1e + 64 + 2 * j);
        a += x3 * ldv2(w1e + 96 + 2 * j);
        h1[j] = relu2(a);
    }

    // layer 2: 32 -> 32
    const float* w2e = W2 + e0 * 1024;
    const float* b2e = b2 + e0 * 32;
    v2f h2[16];
#pragma unroll
    for (int j = 0; j < 16; ++j) h2[j] = ldv2(b2e + 2 * j);
#pragma unroll
    for (int i = 0; i < 32; ++i) {
        float a = (i & 1) ? h1[i >> 1].y : h1[i >> 1].x;
        const float* wr = w2e + i * 32;
#pragma unroll
        for (int j = 0; j < 16; ++j) h2[j] += a * ldv2(wr + 2 * j);
    }
#pragma unroll
    for (int j = 0; j < 16; ++j) h2[j] = relu2(h2[j]);

    // layer 3: 32 -> 64
    const float* w3e = W3 + e0 * 2048;
    const float* b3e = b3 + e0 * 64;
    v2f h3[32];
#pragma unroll
    for (int j = 0; j < 32; ++j) h3[j] = ldv2(b3e + 2 * j);
#pragma unroll
    for (int i = 0; i < 32; ++i) {
        float a = (i & 1) ? h2[i >> 1].y : h2[i >> 1].x;
        const float* wr = w3e + i * 64;
#pragma unroll
        for (int j = 0; j < 32; ++j) h3[j] += a * ldv2(wr + 2 * j);
    }

    // layer 4 collapsed: relu(h3) . rowsum(W4) + sum(b4)
    const float* w4e = w4s + e0 * 64;
    v2f acc = {0.f, 0.f};
#pragma unroll
    for (int j = 0; j < 32; ++j) {
        v2f h = relu2(h3[j]);
        acc += h * ldv2(w4e + 2 * j);
    }
    float pred = acc.x + acc.y + b4s[e0];
    if (valid) out[idx] = pred;
}

// ---------------- fallback (ws too small): divergent, correct ----------------
__global__ __launch_bounds__(256) void k_fallback(const float* __restrict__ feat,
                                                  const float* __restrict__ W1, const float* __restrict__ b1,
                                                  const float* __restrict__ W2, const float* __restrict__ b2,
                                                  const float* __restrict__ W3, const float* __restrict__ b3,
                                                  const float* __restrict__ W4, const float* __restrict__ b4,
                                                  float* __restrict__ out, int n) {
    int i = blockIdx.x * 256 + threadIdx.x;
    if (i >= n) return;
    const float* f = feat + (size_t)i * 5;
    int e = expert_of(f[0]);
    float x0 = f[1], x1 = f[2], x2 = f[3], x3 = f[4];

    const float* w1e = W1 + e * 128;
    const float* b1e = b1 + e * 32;
    v2f h1[16];
#pragma unroll
    for (int j = 0; j < 16; ++j) {
        v2f a = ldv2(b1e + 2 * j);
        a += x0 * ldv2(w1e + 2 * j);
        a += x1 * ldv2(w1e + 32 + 2 * j);
        a += x2 * ldv2(w1e + 64 + 2 * j);
        a += x3 * ldv2(w1e + 96 + 2 * j);
        h1[j] = relu2(a);
    }
    const float* w2e = W2 + e * 1024;
    const float* b2e = b2 + e * 32;
    v2f h2[16];
#pragma unroll
    for (int j = 0; j < 16; ++j) h2[j] = ldv2(b2e + 2 * j);
#pragma unroll
    for (int i2 = 0; i2 < 32; ++i2) {
        float a = (i2 & 1) ? h1[i2 >> 1].y : h1[i2 >> 1].x;
        const float* wr = w2e + i2 * 32;
#pragma unroll
        for (int j = 0; j < 16; ++j) h2[j] += a * ldv2(wr + 2 * j);
    }
#pragma unroll
    for (int j = 0; j < 16; ++j) h2[j] = relu2(h2[j]);

    const float* w3e = W3 + e * 2048;
    const float* b3e = b3 + e * 64;
    v2f h3[32];
#pragma unroll
    for (int j = 0; j < 32; ++j) h3[j] = ldv2(b3e + 2 * j);
#pragma unroll
    for (int i2 = 0; i2 < 32; ++i2) {
        float a = (i2 & 1) ? h2[i2 >> 1].y : h2[i2 >> 1].x;
        const float* wr = w3e + i2 * 64;
#pragma unroll
        for (int j = 0; j < 32; ++j) h3[j] += a * ldv2(wr + 2 * j);
    }
    const float* w4 = W4 + e * 4096;
    const float* b4e = b4 + e * 64;
    float pred = 0.f;
    for (int o = 0; o < 64; ++o) pred += b4e[o];
    for (int j = 0; j < 32; ++j) {
        const float* r0 = w4 + (2 * j) * 64;
        const float* r1 = w4 + (2 * j + 1) * 64;
        float rs0 = 0.f, rs1 = 0.f;
        for (int o = 0; o < 64; ++o) { rs0 += r0[o]; rs1 += r1[o]; }
        v2f h = relu2(h3[j]);
        pred += h.x * rs0 + h.y * rs1;
    }
    out[i] = pred;
}

extern "C" void kernel_launch(void* const* d_in, const int* in_sizes, int n_in,
                              void* d_out, int out_size, void* d_ws, size_t ws_size,
                              hipStream_t stream) {
    const float* feat = (const float*)d_in[0];
    const float* W1 = (const float*)d_in[1];
    const float* b1 = (const float*)d_in[2];
    const float* W2 = (const float*)d_in[3];
    const float* b2 = (const float*)d_in[4];
    const float* W3 = (const float*)d_in[5];
    const float* b3 = (const float*)d_in[6];
    const float* W4 = (const float*)d_in[7];
    const float* b4 = (const float*)d_in[8];
    float* out = (float*)d_out;
    int n = in_sizes[0] / 5;

    // ws layout
    const size_t off_hist = 0, off_pos = 64, off_base = 128, off_b4s = 192, off_w4s = 256;
    const size_t off_karr = 4096;
    const size_t off_idx = off_karr + (size_t)((n + 3) & ~3);
    const size_t need = off_idx + 4 * ((size_t)n + NEXP * 64);

    int blocks = (n + 255) / 256;
    if (ws_size >= need) {
        char* ws = (char*)d_ws;
        int* hist = (int*)(ws + off_hist);
        int* pos = (int*)(ws + off_pos);
        int* base = (int*)(ws + off_base);
        float* b4s = (float*)(ws + off_b4s);
        float* w4s = (float*)(ws + off_w4s);
        uint8_t* karr = (uint8_t*)(ws + off_karr);
        unsigned* idxb = (unsigned*)(ws + off_idx);

        hipMemsetAsync(ws, 0, 256, stream);
        k_hist<<<blocks, 256, 0, stream>>>(feat, n, hist, karr);
        k_prep<<<1, 1024, 0, stream>>>(hist, W4, b4, base, w4s, b4s);
        k_scatter<<<blocks, 256, 0, stream>>>(karr, n, base, pos, idxb);
        int blocks4 = (n + NEXP * 64 + 255) / 256;
        k_mlp<<<blocks4, 256, 0, stream>>>(feat, W1, b1, W2, b2, W3, b3,
                                           hist, base, w4s, b4s, idxb, out, n);
    } else {
        k_fallback<<<blocks, 256, 0, stream>>>(feat, W1, b1, W2, b2, W3, b3, W4, b4, out, n);
    }
}

// Round 2
// 67.597 us; speedup vs baseline: 2.9562x; 2.9562x over previous
//
#include <hip/hip_runtime.h>
#include <stdint.h>

#define NEXP 9
#define CAP 131072               // per-expert padded bucket capacity (mean ~116.5k, +45 sigma)
#define TBL_CHUNKS 32            // 32 chunks x 1024B = 32KB per expert
#define TBL_BYTES (TBL_CHUNKS * 1024)

typedef float f32x4 __attribute__((ext_vector_type(4)));
typedef float f32x16 __attribute__((ext_vector_type(16)));
typedef _Float16 f16x8 __attribute__((ext_vector_type(8)));
typedef float v2f __attribute__((ext_vector_type(2)));

struct alignas(16) I4 { int a, b, c, d; };
struct alignas(64) Q4 { f32x4 a, b, c, d; };

__device__ __forceinline__ int expert_of(float fr) {
    const float frs[NEXP] = {1.f, 2.f, 4.f, 8.f, 16.f, 25.f, 36.f, 50.f, 75.f};
    int k = 0;
    float best = fabsf(fr - frs[0]);
#pragma unroll
    for (int e = 1; e < NEXP; ++e) {
        float d = fabsf(fr - frs[e]);
        if (d < best) { best = d; k = e; }
    }
    return k;
}

// ---------------- K_prep: prepack per-expert tables in MFMA fragment layout ----------------
// Chunk map (chunk = 1024B = 64 lanes x 16B):
//  0        : A1  = W1^T padded to K=16, f16 frag (row=lane&31, k=(lane>>5)*8+e)
//  1..2     : A2  frags kf=0,1 (K=32 split into 2x16)
//  3..6     : A3  frags (t=M-tile 0/1) x (kf 0/1):  3 + t*2 + kf
//  7..10    : C1  = b1 in D layout (chunk c holds regs 4c..4c+3; row=(r&3)+8*(r>>2)+4g)
// 11..14    : C2  = b2 in D layout
// 15..22    : C3  = b3 in D layout, tiles t=0,1: 15 + t*4 + c
// 23..30    : W4D = rowsum(W4) in D layout, tiles: 23 + t*4 + c
// 31       : b4s = sum(b4) replicated
__global__ __launch_bounds__(64) void k_prep(const float* __restrict__ W1, const float* __restrict__ b1,
                                             const float* __restrict__ W2, const float* __restrict__ b2,
                                             const float* __restrict__ W3, const float* __restrict__ b3,
                                             const float* __restrict__ W4, const float* __restrict__ b4,
                                             char* __restrict__ tab) {
    int e = blockIdx.x;
    int l = threadIdx.x;          // lane 0..63
    int g = l >> 5, m = l & 31;
    char* T = tab + (size_t)e * TBL_BYTES;

    // A1: W1 is [4][32] (din,dout); A1[row][k] = W1[k][row], k<4 else 0
    {
        f16x8 v;
#pragma unroll
        for (int ei = 0; ei < 8; ++ei) {
            int k = g * 8 + ei;
            float w = (k < 4) ? W1[e * 128 + k * 32 + m] : 0.f;
            v[ei] = (_Float16)w;
        }
        *(f16x8*)(T + 0 * 1024 + l * 16) = v;
    }
    // A2: W2 [32][32]
#pragma unroll
    for (int kf = 0; kf < 2; ++kf) {
        f16x8 v;
#pragma unroll
        for (int ei = 0; ei < 8; ++ei) {
            int k = kf * 16 + g * 8 + ei;
            v[ei] = (_Float16)W2[e * 1024 + k * 32 + m];
        }
        *(f16x8*)(T + (1 + kf) * 1024 + l * 16) = v;
    }
    // A3: W3 [32][64]
#pragma unroll
    for (int t = 0; t < 2; ++t)
#pragma unroll
        for (int kf = 0; kf < 2; ++kf) {
            f16x8 v;
            int row = t * 32 + m;
#pragma unroll
            for (int ei = 0; ei < 8; ++ei) {
                int k = kf * 16 + g * 8 + ei;
                v[ei] = (_Float16)W3[e * 2048 + k * 64 + row];
            }
            *(f16x8*)(T + (3 + t * 2 + kf) * 1024 + l * 16) = v;
        }
    // C1, C2 (b1,b2 are [32])
#pragma unroll
    for (int c = 0; c < 4; ++c) {
        f32x4 v1, v2;
#pragma unroll
        for (int j = 0; j < 4; ++j) {
            int r = c * 4 + j;
            int row = (r & 3) + 8 * (r >> 2) + 4 * g;
            v1[j] = b1[e * 32 + row];
            v2[j] = b2[e * 32 + row];
        }
        *(f32x4*)(T + (7 + c) * 1024 + l * 16) = v1;
        *(f32x4*)(T + (11 + c) * 1024 + l * 16) = v2;
    }
    // C3 (b3 is [64])
#pragma unroll
    for (int t = 0; t < 2; ++t)
#pragma unroll
        for (int c = 0; c < 4; ++c) {
            f32x4 v;
#pragma unroll
            for (int j = 0; j < 4; ++j) {
                int r = c * 4 + j;
                int row = 32 * t + (r & 3) + 8 * (r >> 2) + 4 * g;
                v[j] = b3[e * 64 + row];
            }
            *(f32x4*)(T + (15 + t * 4 + c) * 1024 + l * 16) = v;
        }
    // W4 rowsums + b4 sum
    __shared__ float rs[64];
    {
        float s = 0.f;
        const float* w = W4 + (size_t)e * 4096 + l * 64;
        for (int o = 0; o < 64; ++o) s += w[o];
        rs[l] = s;
    }
    float bp = b4[e * 64 + l];
#pragma unroll
    for (int d = 1; d < 64; d <<= 1) bp += __shfl_xor(bp, d, 64);
    __syncthreads();
#pragma unroll
    for (int t = 0; t < 2; ++t)
#pragma unroll
        for (int c = 0; c < 4; ++c) {
            f32x4 v;
#pragma unroll
            for (int j = 0; j < 4; ++j) {
                int r = c * 4 + j;
                int row = 32 * t + (r & 3) + 8 * (r >> 2) + 4 * g;
                v[j] = rs[row];
            }
            *(f32x4*)(T + (23 + t * 4 + c) * 1024 + l * 16) = v;
        }
    f32x4 bb = {bp, bp, bp, bp};
    *(f32x4*)(T + 31 * 1024 + l * 16) = bb;
}

// ---------------- K_route: fused expert-id + block-aggregated scatter ----------------
__global__ __launch_bounds__(512) void k_route(const float* __restrict__ feat, int n,
                                               int* __restrict__ pos,
                                               unsigned* __restrict__ idxb) {
    __shared__ int wcnt[8][NEXP];
    __shared__ int bbase[NEXP];
    int tid = threadIdx.x;
    int i = blockIdx.x * 512 + tid;
    int wid = tid >> 6, lane = tid & 63;
    int k = -1;
    if (i < n) k = expert_of(feat[(size_t)i * 5]);
    unsigned long long myM = 0;
#pragma unroll
    for (int e = 0; e < NEXP; ++e) {
        unsigned long long mm = __ballot(k == e);
        if (lane == 0) wcnt[wid][e] = __popcll(mm);
        if (k == e) myM = mm;
    }
    __syncthreads();
    if (tid < NEXP) {
        int tot = 0;
#pragma unroll
        for (int w = 0; w < 8; ++w) tot += wcnt[w][tid];
        bbase[tid] = tot ? atomicAdd(&pos[tid], tot) : 0;
    }
    __syncthreads();
    if (k >= 0) {
        int before = 0;
        for (int w = 0; w < wid; ++w) before += wcnt[w][k];
        int rank = __popcll(myM & ((1ull << lane) - 1ull));
        idxb[(size_t)k * CAP + bbase[k] + before + rank] = (unsigned)i;
    }
}

// ---------------- transition: D (f32x16, post-relu) -> two B frags (f16x8) ----------------
__device__ __forceinline__ int pk(float a, float b) {
    return __builtin_bit_cast(int, __builtin_amdgcn_cvt_pkrtz(a, b));
}
__device__ __forceinline__ void d2b(const f32x16 d, bool G, f16x8& f0, f16x8& f1) {
    int p01 = pk(d[0], d[1]), p23 = pk(d[2], d[3]), p45 = pk(d[4], d[5]), p67 = pk(d[6], d[7]);
    int p89 = pk(d[8], d[9]), pab = pk(d[10], d[11]), pcd = pk(d[12], d[13]), pef = pk(d[14], d[15]);
    int s01 = __shfl_xor(p01, 32, 64), s23 = __shfl_xor(p23, 32, 64);
    int s45 = __shfl_xor(p45, 32, 64), s67 = __shfl_xor(p67, 32, 64);
    int s89 = __shfl_xor(p89, 32, 64), sab = __shfl_xor(pab, 32, 64);
    int scd = __shfl_xor(pcd, 32, 64), sef = __shfl_xor(pef, 32, 64);
    I4 t0 = {G ? s45 : p01, G ? s67 : p23, G ? p45 : s01, G ? p67 : s23};
    I4 t1 = {G ? scd : p89, G ? sef : pab, G ? pcd : s89, G ? pef : sab};
    f0 = __builtin_bit_cast(f16x8, t0);
    f1 = __builtin_bit_cast(f16x8, t1);
}

// ---------------- K_mlp: MFMA expert MLP, 32 samples per wave ----------------
__global__ __launch_bounds__(512) void k_mlp(const float* __restrict__ feat,
                                             const int* __restrict__ pos,
                                             const unsigned* __restrict__ idxb,
                                             const char* __restrict__ tab,
                                             float* __restrict__ out) {
    const int bpe = CAP / 256;   // blocks per expert (256 samples per 512-thread block)
    int e = blockIdx.x / bpe;
    int tile = blockIdx.x % bpe;
    int count = pos[e];
    if (tile * 256 >= count) return;

    __shared__ char sm[TBL_BYTES];
    {
        const char* T = tab + (size_t)e * TBL_BYTES;
        int tid = threadIdx.x;
#pragma unroll
        for (int it = 0; it < 4; ++it) {
            int off = (it * 512 + tid) * 16;
            *(f32x4*)(sm + off) = *(const f32x4*)(T + off);
        }
    }
    __syncthreads();

    int tid = threadIdx.x;
    int wid = tid >> 6, lane = tid & 63, g = lane >> 5, m = lane & 31;
    bool G = g != 0;
    int sl = tile * 256 + wid * 32 + m;
    bool valid = sl < count;
    unsigned idx = 0;
    float x0 = 0.f, x1 = 0.f, x2 = 0.f, x3 = 0.f;
    if (valid) {
        idx = idxb[(size_t)e * CAP + sl];
        if (!G) {
            const float* f = feat + (size_t)idx * 5;
            x0 = f[1]; x1 = f[2]; x2 = f[3]; x3 = f[4];
        }
    }

    // B1: x^T padded to K=16 (only g=0, k0..3 nonzero; zeros elsewhere)
    I4 b1w = {pk(x0, x1), pk(x2, x3), 0, 0};
    f16x8 B1 = __builtin_bit_cast(f16x8, b1w);

    auto ldA = [&](int chunk) -> f16x8 {
        return *(const f16x8*)(sm + chunk * 1024 + lane * 16);
    };
    auto ldC = [&](int chunk) -> f32x16 {
        Q4 q;
        q.a = *(const f32x4*)(sm + (chunk + 0) * 1024 + lane * 16);
        q.b = *(const f32x4*)(sm + (chunk + 1) * 1024 + lane * 16);
        q.c = *(const f32x4*)(sm + (chunk + 2) * 1024 + lane * 16);
        q.d = *(const f32x4*)(sm + (chunk + 3) * 1024 + lane * 16);
        return __builtin_bit_cast(f32x16, q);
    };

    // L1: h1 = relu(W1^T x + b1)   [32f x 32s]
    f32x16 d1 = __builtin_amdgcn_mfma_f32_32x32x16_f16(ldA(0), B1, ldC(7), 0, 0, 0);
#pragma unroll
    for (int r = 0; r < 16; ++r) d1[r] = fmaxf(d1[r], 0.f);
    f16x8 B2a, B2b;
    d2b(d1, G, B2a, B2b);

    // L2: h2 = relu(W2^T h1 + b2)  [32f x 32s], K=32 via 2 mfma
    f32x16 d2 = __builtin_amdgcn_mfma_f32_32x32x16_f16(ldA(1), B2a, ldC(11), 0, 0, 0);
    d2 = __builtin_amdgcn_mfma_f32_32x32x16_f16(ldA(2), B2b, d2, 0, 0, 0);
#pragma unroll
    for (int r = 0; r < 16; ++r) d2[r] = fmaxf(d2[r], 0.f);
    f16x8 B3a, B3b;
    d2b(d2, G, B3a, B3b);

    // L3 tile0 (outf 0..31) + fused relu-dot with rowsum(W4)
    float acc = 0.f;
    {
        f32x16 d3 = __builtin_amdgcn_mfma_f32_32x32x16_f16(ldA(3), B3a, ldC(15), 0, 0, 0);
        d3 = __builtin_amdgcn_mfma_f32_32x32x16_f16(ldA(4), B3b, d3, 0, 0, 0);
        f32x16 w = ldC(23);
#pragma unroll
        for (int r = 0; r < 16; ++r) acc += fmaxf(d3[r], 0.f) * w[r];
    }
    // L3 tile1 (outf 32..63)
    {
        f32x16 d3 = __builtin_amdgcn_mfma_f32_32x32x16_f16(ldA(5), B3a, ldC(19), 0, 0, 0);
        d3 = __builtin_amdgcn_mfma_f32_32x32x16_f16(ldA(6), B3b, d3, 0, 0, 0);
        f32x16 w = ldC(27);
#pragma unroll
        for (int r = 0; r < 16; ++r) acc += fmaxf(d3[r], 0.f) * w[r];
    }
    acc += __shfl_xor(acc, 32, 64);
    float b4v = *(const float*)(sm + 31 * 1024);
    if (valid && !G) out[idx] = acc + b4v;
}

// ---------------- fallback (ws too small): divergent, correct ----------------
__global__ __launch_bounds__(256) void k_fallback(const float* __restrict__ feat,
                                                  const float* __restrict__ W1, const float* __restrict__ b1,
                                                  const float* __restrict__ W2, const float* __restrict__ b2,
                                                  const float* __restrict__ W3, const float* __restrict__ b3,
                                                  const float* __restrict__ W4, const float* __restrict__ b4,
                                                  float* __restrict__ out, int n) {
    int i = blockIdx.x * 256 + threadIdx.x;
    if (i >= n) return;
    const float* f = feat + (size_t)i * 5;
    int e = expert_of(f[0]);
    float x0 = f[1], x1 = f[2], x2 = f[3], x3 = f[4];
    float h1[32], h2[32], h3[64];
    for (int j = 0; j < 32; ++j) {
        float a = b1[e * 32 + j];
        a += x0 * W1[e * 128 + 0 * 32 + j];
        a += x1 * W1[e * 128 + 1 * 32 + j];
        a += x2 * W1[e * 128 + 2 * 32 + j];
        a += x3 * W1[e * 128 + 3 * 32 + j];
        h1[j] = fmaxf(a, 0.f);
    }
    for (int j = 0; j < 32; ++j) h2[j] = b2[e * 32 + j];
    for (int i2 = 0; i2 < 32; ++i2)
        for (int j = 0; j < 32; ++j) h2[j] += h1[i2] * W2[e * 1024 + i2 * 32 + j];
    for (int j = 0; j < 32; ++j) h2[j] = fmaxf(h2[j], 0.f);
    for (int j = 0; j < 64; ++j) h3[j] = b3[e * 64 + j];
    for (int i2 = 0; i2 < 32; ++i2)
        for (int j = 0; j < 64; ++j) h3[j] += h2[i2] * W3[e * 2048 + i2 * 64 + j];
    float pred = 0.f;
    for (int o = 0; o < 64; ++o) pred += b4[e * 64 + o];
    for (int j = 0; j < 64; ++j) {
        float rs = 0.f;
        for (int o = 0; o < 64; ++o) rs += W4[e * 4096 + j * 64 + o];
        pred += fmaxf(h3[j], 0.f) * rs;
    }
    out[i] = pred;
}

extern "C" void kernel_launch(void* const* d_in, const int* in_sizes, int n_in,
                              void* d_out, int out_size, void* d_ws, size_t ws_size,
                              hipStream_t stream) {
    const float* feat = (const float*)d_in[0];
    const float* W1 = (const float*)d_in[1];
    const float* b1 = (const float*)d_in[2];
    const float* W2 = (const float*)d_in[3];
    const float* b2 = (const float*)d_in[4];
    const float* W3 = (const float*)d_in[5];
    const float* b3 = (const float*)d_in[6];
    const float* W4 = (const float*)d_in[7];
    const float* b4 = (const float*)d_in[8];
    float* out = (float*)d_out;
    int n = in_sizes[0] / 5;

    const size_t off_pos = 0;                       // 9 ints
    const size_t off_tab = 256;                     // 9 * 32KB
    const size_t off_idx = 256 + (size_t)NEXP * TBL_BYTES;
    const size_t need = off_idx + (size_t)NEXP * CAP * 4;

    if (ws_size >= need && n <= CAP * NEXP) {
        char* ws = (char*)d_ws;
        int* pos = (int*)(ws + off_pos);
        char* tab = ws + off_tab;
        unsigned* idxb = (unsigned*)(ws + off_idx);

        hipMemsetAsync(pos, 0, 64, stream);
        k_route<<<(n + 511) / 512, 512, 0, stream>>>(feat, n, pos, idxb);
        k_prep<<<NEXP, 64, 0, stream>>>(W1, b1, W2, b2, W3, b3, W4, b4, tab);
        k_mlp<<<NEXP * (CAP / 256), 512, 0, stream>>>(feat, pos, idxb, tab, out);
    } else {
        k_fallback<<<(n + 255) / 256, 256, 0, stream>>>(feat, W1, b1, W2, b2, W3, b3, W4, b4, out, n);
    }
}

// Round 3
// 56.490 us; speedup vs baseline: 3.5375x; 1.1966x over previous
//
#include <hip/hip_runtime.h>
#include <stdint.h>

#define NEXP 9
#define CAP 131072               // per-expert bucket capacity (mean 116.5k, +46 sigma)
#define NCHUNK 28                // 28 chunks x 1024B = 28KB per expert table
#define TBL_BYTES (NCHUNK * 1024)

typedef float f32x4 __attribute__((ext_vector_type(4)));
typedef float f32x16 __attribute__((ext_vector_type(16)));
typedef _Float16 f16x8 __attribute__((ext_vector_type(8)));

struct alignas(16) I4 { int a, b, c, d; };
struct alignas(64) Q4 { f32x4 a, b, c, d; };

__device__ __forceinline__ int pk(float a, float b) {
    return __builtin_bit_cast(int, __builtin_amdgcn_cvt_pkrtz(a, b));
}
__device__ __forceinline__ f32x16 zero16() {
    f32x16 z;
#pragma unroll
    for (int r = 0; r < 16; ++r) z[r] = 0.f;
    return z;
}

__device__ __forceinline__ int expert_of(float fr) {
    const float frs[NEXP] = {1.f, 2.f, 4.f, 8.f, 16.f, 25.f, 36.f, 50.f, 75.f};
    int k = 0;
    float best = fabsf(fr - frs[0]);
#pragma unroll
    for (int e = 1; e < NEXP; ++e) {
        float d = fabsf(fr - frs[e]);
        if (d < best) { best = d; k = e; }
    }
    return k;
}

// ---------------- K_prep: prepack per-expert tables + zero pos ----------------
// Chunk map (chunk = 1024B = 64 lanes x 16B):
//  0      : A1 = W1^T with b1 folded at k=4 (x4=1.0), k>=5 zero
//  1..2   : A2 frags kf=0,1 — K-permuted: k_hw=8g+e -> row kf*16 + (e&3)+8*(e>>2)+4g
//  3..6   : A3 frags (t, kf) = 3+t*2+kf — same K-permutation
//  7..10  : C2 = b2 in D layout
// 11..18  : C3 = b3 in D layout, 11+t*4+c
// 19..26  : W4D = rowsum(W4) in D layout, 19+t*4+c
// 27     : b4s = sum(b4) replicated
__global__ __launch_bounds__(64) void k_prep(const float* __restrict__ W1, const float* __restrict__ b1,
                                             const float* __restrict__ W2, const float* __restrict__ b2,
                                             const float* __restrict__ W3, const float* __restrict__ b3,
                                             const float* __restrict__ W4, const float* __restrict__ b4,
                                             char* __restrict__ tab, int* __restrict__ pos) {
    int e = blockIdx.x;
    int l = threadIdx.x;
    int g = l >> 5, m = l & 31;
    if (e == 0 && l < 16) pos[l] = 0;
    char* T = tab + (size_t)e * TBL_BYTES;

    // A1
    {
        f16x8 v;
#pragma unroll
        for (int ei = 0; ei < 8; ++ei) {
            int k = g * 8 + ei;
            float w = (k < 4) ? W1[e * 128 + k * 32 + m] : (k == 4 ? b1[e * 32 + m] : 0.f);
            v[ei] = (_Float16)w;
        }
        *(f16x8*)(T + 0 * 1024 + l * 16) = v;
    }
    // A2 (K-permuted)
#pragma unroll
    for (int kf = 0; kf < 2; ++kf) {
        f16x8 v;
#pragma unroll
        for (int ei = 0; ei < 8; ++ei) {
            int row = kf * 16 + (ei & 3) + 8 * (ei >> 2) + 4 * g;
            v[ei] = (_Float16)W2[e * 1024 + row * 32 + m];
        }
        *(f16x8*)(T + (1 + kf) * 1024 + l * 16) = v;
    }
    // A3 (K-permuted)
#pragma unroll
    for (int t = 0; t < 2; ++t)
#pragma unroll
        for (int kf = 0; kf < 2; ++kf) {
            f16x8 v;
#pragma unroll
            for (int ei = 0; ei < 8; ++ei) {
                int row = kf * 16 + (ei & 3) + 8 * (ei >> 2) + 4 * g;
                v[ei] = (_Float16)W3[e * 2048 + row * 64 + t * 32 + m];
            }
            *(f16x8*)(T + (3 + t * 2 + kf) * 1024 + l * 16) = v;
        }
    // C2
#pragma unroll
    for (int c = 0; c < 4; ++c) {
        f32x4 v;
#pragma unroll
        for (int j = 0; j < 4; ++j) {
            int r = c * 4 + j;
            int row = (r & 3) + 8 * (r >> 2) + 4 * g;
            v[j] = b2[e * 32 + row];
        }
        *(f32x4*)(T + (7 + c) * 1024 + l * 16) = v;
    }
    // C3
#pragma unroll
    for (int t = 0; t < 2; ++t)
#pragma unroll
        for (int c = 0; c < 4; ++c) {
            f32x4 v;
#pragma unroll
            for (int j = 0; j < 4; ++j) {
                int r = c * 4 + j;
                int row = t * 32 + (r & 3) + 8 * (r >> 2) + 4 * g;
                v[j] = b3[e * 64 + row];
            }
            *(f32x4*)(T + (11 + t * 4 + c) * 1024 + l * 16) = v;
        }
    // W4 rowsums + b4 sum
    __shared__ float rs[64];
    {
        float s = 0.f;
        const float* w = W4 + (size_t)e * 4096 + l * 64;
        for (int o = 0; o < 64; ++o) s += w[o];
        rs[l] = s;
    }
    float bp = b4[e * 64 + l];
#pragma unroll
    for (int d = 1; d < 64; d <<= 1) bp += __shfl_xor(bp, d, 64);
    __syncthreads();
#pragma unroll
    for (int t = 0; t < 2; ++t)
#pragma unroll
        for (int c = 0; c < 4; ++c) {
            f32x4 v;
#pragma unroll
            for (int j = 0; j < 4; ++j) {
                int r = c * 4 + j;
                int row = t * 32 + (r & 3) + 8 * (r >> 2) + 4 * g;
                v[j] = rs[row];
            }
            *(f32x4*)(T + (19 + t * 4 + c) * 1024 + l * 16) = v;
        }
    f32x4 bb = {bp, bp, bp, bp};
    *(f32x4*)(T + 27 * 1024 + l * 16) = bb;
}

// ---------------- K_route: expert-id + scatter idx and f16-packed x ----------------
__global__ __launch_bounds__(512) void k_route(const float* __restrict__ feat, int n,
                                               int* __restrict__ pos,
                                               unsigned* __restrict__ idxb,
                                               uint2* __restrict__ xbuf) {
    __shared__ int wcnt[8][NEXP];
    __shared__ int bbase[NEXP];
    int tid = threadIdx.x;
    int i = blockIdx.x * 512 + tid;
    int wid = tid >> 6, lane = tid & 63;
    int k = -1;
    if (i < n) k = expert_of(feat[(size_t)i * 5]);
    unsigned long long myM = 0;
#pragma unroll
    for (int e = 0; e < NEXP; ++e) {
        unsigned long long mm = __ballot(k == e);
        if (lane == 0) wcnt[wid][e] = __popcll(mm);
        if (k == e) myM = mm;
    }
    __syncthreads();
    if (tid < NEXP) {
        int tot = 0;
#pragma unroll
        for (int w = 0; w < 8; ++w) tot += wcnt[w][tid];
        bbase[tid] = tot ? atomicAdd(&pos[tid], tot) : 0;
    }
    __syncthreads();
    if (k >= 0) {
        int before = 0;
        for (int w = 0; w < wid; ++w) before += wcnt[w][k];
        int rank = __popcll(myM & ((1ull << lane) - 1ull));
        int slot = bbase[k] + before + rank;
        if (slot < CAP) {
            const float* f = feat + (size_t)i * 5;
            uint2 w;
            w.x = (unsigned)pk(f[1], f[2]);
            w.y = (unsigned)pk(f[3], f[4]);
            idxb[(size_t)k * CAP + slot] = (unsigned)i;
            xbuf[(size_t)k * CAP + slot] = w;
        }
    }
}

// ---------------- K_mlp: 4 tiles (128 samples) per wave, persistent fragments ----------------
__global__ __launch_bounds__(256, 3) void k_mlp(const int* __restrict__ pos,
                                                const uint2* __restrict__ xbuf,
                                                const unsigned* __restrict__ idxb,
                                                const char* __restrict__ tab,
                                                float* __restrict__ out) {
    const int bpe = CAP / 512;        // 256 blocks per expert, 512 samples each
    int e = blockIdx.x / bpe;
    int tile = blockIdx.x % bpe;
    int count = pos[e];
    count = count < CAP ? count : CAP;
    int base = tile * 512;
    if (base >= count) return;

    __shared__ char sm[TBL_BYTES];
    {
        const char* T = tab + (size_t)e * TBL_BYTES;
        int tid = threadIdx.x;
#pragma unroll
        for (int it = 0; it < 7; ++it) {
            int off = (it * 256 + tid) * 16;
            *(f32x4*)(sm + off) = *(const f32x4*)(T + off);
        }
    }
    __syncthreads();

    int tid = threadIdx.x;
    int wid = tid >> 6, lane = tid & 63, g = lane >> 5, m = lane & 31;
    int wbase = base + wid * 128;
    if (wbase >= count) return;       // wave-uniform; no barriers after this

    auto ldA = [&](int chunk) -> f16x8 {
        return *(const f16x8*)(sm + chunk * 1024 + lane * 16);
    };
    auto ldC = [&](int chunk) -> f32x16 {
        Q4 q;
        q.a = *(const f32x4*)(sm + (chunk + 0) * 1024 + lane * 16);
        q.b = *(const f32x4*)(sm + (chunk + 1) * 1024 + lane * 16);
        q.c = *(const f32x4*)(sm + (chunk + 2) * 1024 + lane * 16);
        q.d = *(const f32x4*)(sm + (chunk + 3) * 1024 + lane * 16);
        return __builtin_bit_cast(f32x16, q);
    };

    // persistent fragments
    f16x8 A1 = ldA(0);
    f16x8 A2a = ldA(1), A2b = ldA(2);
    f16x8 A30a = ldA(3), A30b = ldA(4), A31a = ldA(5), A31b = ldA(6);
    f32x16 C2 = ldC(7);
    f32x16 C30 = ldC(11), C31 = ldC(15);
    f32x16 W40 = ldC(19), W41 = ldC(23);
    float b4v = *(const float*)(sm + 27 * 1024);

    // sample data (4 tiles of 32)
    uint2 xt[4];
#pragma unroll
    for (int t = 0; t < 4; ++t) {
        int sl = wbase + t * 32 + m;
        bool v = sl < count;
        uint2 w = {0u, 0u};
        if (v) w = xbuf[(size_t)e * CAP + sl];
        xt[t] = w;
    }
    // store targets: g=0 stores tiles 0,1; g=1 stores tiles 2,3
    int sA = wbase + g * 64 + m;
    int sB = wbase + g * 64 + 32 + m;
    bool vA = sA < count, vB = sB < count;
    unsigned iA = vA ? idxb[(size_t)e * CAP + sA] : 0u;
    unsigned iB = vB ? idxb[(size_t)e * CAP + sB] : 0u;

    float res[4];
#pragma unroll
    for (int t = 0; t < 4; ++t) {
        // B1: g=0 lanes carry (x0,x1,x2,x3,1); g=1 half is zero K-rows
        I4 b1i = {g ? 0 : (int)xt[t].x, g ? 0 : (int)xt[t].y, g ? 0 : 0x3C00, 0};
        f16x8 B1 = __builtin_bit_cast(f16x8, b1i);

        f32x16 d1 = __builtin_amdgcn_mfma_f32_32x32x16_f16(A1, B1, zero16(), 0, 0, 0);
#pragma unroll
        for (int r = 0; r < 16; ++r) d1[r] = fmaxf(d1[r], 0.f);
        // natural packing — K-permutation is baked into A2/A3
        I4 p0 = {pk(d1[0], d1[1]), pk(d1[2], d1[3]), pk(d1[4], d1[5]), pk(d1[6], d1[7])};
        I4 p1 = {pk(d1[8], d1[9]), pk(d1[10], d1[11]), pk(d1[12], d1[13]), pk(d1[14], d1[15])};
        f16x8 B2a = __builtin_bit_cast(f16x8, p0);
        f16x8 B2b = __builtin_bit_cast(f16x8, p1);

        f32x16 d2 = __builtin_amdgcn_mfma_f32_32x32x16_f16(A2a, B2a, C2, 0, 0, 0);
        d2 = __builtin_amdgcn_mfma_f32_32x32x16_f16(A2b, B2b, d2, 0, 0, 0);
#pragma unroll
        for (int r = 0; r < 16; ++r) d2[r] = fmaxf(d2[r], 0.f);
        I4 q0 = {pk(d2[0], d2[1]), pk(d2[2], d2[3]), pk(d2[4], d2[5]), pk(d2[6], d2[7])};
        I4 q1 = {pk(d2[8], d2[9]), pk(d2[10], d2[11]), pk(d2[12], d2[13]), pk(d2[14], d2[15])};
        f16x8 B3a = __builtin_bit_cast(f16x8, q0);
        f16x8 B3b = __builtin_bit_cast(f16x8, q1);

        float acc = 0.f;
        {
            f32x16 d3 = __builtin_amdgcn_mfma_f32_32x32x16_f16(A30a, B3a, C30, 0, 0, 0);
            d3 = __builtin_amdgcn_mfma_f32_32x32x16_f16(A30b, B3b, d3, 0, 0, 0);
#pragma unroll
            for (int r = 0; r < 16; ++r) acc += fmaxf(d3[r], 0.f) * W40[r];
        }
        {
            f32x16 d3 = __builtin_amdgcn_mfma_f32_32x32x16_f16(A31a, B3a, C31, 0, 0, 0);
            d3 = __builtin_amdgcn_mfma_f32_32x32x16_f16(A31b, B3b, d3, 0, 0, 0);
#pragma unroll
            for (int r = 0; r < 16; ++r) acc += fmaxf(d3[r], 0.f) * W41[r];
        }
        acc += __shfl_xor(acc, 32, 64);
        res[t] = acc + b4v;
    }
    float rA = g ? res[2] : res[0];
    float rB = g ? res[3] : res[1];
    if (vA) out[iA] = rA;
    if (vB) out[iB] = rB;
}

// ---------------- fallback (ws too small): divergent, correct ----------------
__global__ __launch_bounds__(256) void k_fallback(const float* __restrict__ feat,
                                                  const float* __restrict__ W1, const float* __restrict__ b1,
                                                  const float* __restrict__ W2, const float* __restrict__ b2,
                                                  const float* __restrict__ W3, const float* __restrict__ b3,
                                                  const float* __restrict__ W4, const float* __restrict__ b4,
                                                  float* __restrict__ out, int n) {
    int i = blockIdx.x * 256 + threadIdx.x;
    if (i >= n) return;
    const float* f = feat + (size_t)i * 5;
    int e = expert_of(f[0]);
    float x0 = f[1], x1 = f[2], x2 = f[3], x3 = f[4];
    float h1[32], h2[32], h3[64];
    for (int j = 0; j < 32; ++j) {
        float a = b1[e * 32 + j];
        a += x0 * W1[e * 128 + 0 * 32 + j];
        a += x1 * W1[e * 128 + 1 * 32 + j];
        a += x2 * W1[e * 128 + 2 * 32 + j];
        a += x3 * W1[e * 128 + 3 * 32 + j];
        h1[j] = fmaxf(a, 0.f);
    }
    for (int j = 0; j < 32; ++j) h2[j] = b2[e * 32 + j];
    for (int i2 = 0; i2 < 32; ++i2)
        for (int j = 0; j < 32; ++j) h2[j] += h1[i2] * W2[e * 1024 + i2 * 32 + j];
    for (int j = 0; j < 32; ++j) h2[j] = fmaxf(h2[j], 0.f);
    for (int j = 0; j < 64; ++j) h3[j] = b3[e * 64 + j];
    for (int i2 = 0; i2 < 32; ++i2)
        for (int j = 0; j < 64; ++j) h3[j] += h2[i2] * W3[e * 2048 + i2 * 64 + j];
    float pred = 0.f;
    for (int o = 0; o < 64; ++o) pred += b4[e * 64 + o];
    for (int j = 0; j < 64; ++j) {
        float rsum = 0.f;
        for (int o = 0; o < 64; ++o) rsum += W4[e * 4096 + j * 64 + o];
        pred += fmaxf(h3[j], 0.f) * rsum;
    }
    out[i] = pred;
}

extern "C" void kernel_launch(void* const* d_in, const int* in_sizes, int n_in,
                              void* d_out, int out_size, void* d_ws, size_t ws_size,
                              hipStream_t stream) {
    const float* feat = (const float*)d_in[0];
    const float* W1 = (const float*)d_in[1];
    const float* b1 = (const float*)d_in[2];
    const float* W2 = (const float*)d_in[3];
    const float* b2 = (const float*)d_in[4];
    const float* W3 = (const float*)d_in[5];
    const float* b3 = (const float*)d_in[6];
    const float* W4 = (const float*)d_in[7];
    const float* b4 = (const float*)d_in[8];
    float* out = (float*)d_out;
    int n = in_sizes[0] / 5;

    const size_t off_pos = 0;                                  // 64 B
    const size_t off_tab = 256;                                // 9 * 28 KB
    const size_t off_x = off_tab + (size_t)NEXP * TBL_BYTES;   // 9 * CAP * 8 B
    const size_t off_idx = off_x + (size_t)NEXP * CAP * 8;     // 9 * CAP * 4 B
    const size_t need = off_idx + (size_t)NEXP * CAP * 4;

    if (ws_size >= need && n <= CAP * NEXP) {
        char* ws = (char*)d_ws;
        int* pos = (int*)(ws + off_pos);
        char* tab = ws + off_tab;
        uint2* xbuf = (uint2*)(ws + off_x);
        unsigned* idxb = (unsigned*)(ws + off_idx);

        k_prep<<<NEXP, 64, 0, stream>>>(W1, b1, W2, b2, W3, b3, W4, b4, tab, pos);
        k_route<<<(n + 511) / 512, 512, 0, stream>>>(feat, n, pos, idxb, xbuf);
        k_mlp<<<NEXP * (CAP / 512), 256, 0, stream>>>(pos, xbuf, idxb, tab, out);
    } else {
        k_fallback<<<(n + 255) / 256, 256, 0, stream>>>(feat, W1, b1, W2, b2, W3, b3, W4, b4, out, n);
    }
}

// Round 4
// 43.914 us; speedup vs baseline: 4.5505x; 1.2864x over previous
//
#include <hip/hip_runtime.h>
#include <stdint.h>

#define NEXP 9
#define CAP 131072               // per-expert bucket capacity (mean 116.5k, +46 sigma)
#define NCHUNK 28                // 28 chunks x 1024B = 28KB per expert table
#define TBL_BYTES (NCHUNK * 1024)
#define RBLK 4096                // samples per routing block
#define POSPAD 16                // ints between counters (64B)

typedef float f32x4 __attribute__((ext_vector_type(4)));
typedef float f32x16 __attribute__((ext_vector_type(16)));
typedef _Float16 f16x8 __attribute__((ext_vector_type(8)));

struct alignas(16) I4 { int a, b, c, d; };
struct alignas(64) Q4 { f32x4 a, b, c, d; };

__device__ __forceinline__ int pk(float a, float b) {
    return __builtin_bit_cast(int, __builtin_amdgcn_cvt_pkrtz(a, b));
}
__device__ __forceinline__ f32x16 zero16() {
    f32x16 z;
#pragma unroll
    for (int r = 0; r < 16; ++r) z[r] = 0.f;
    return z;
}

__device__ __forceinline__ int expert_of(float fr) {
    const float frs[NEXP] = {1.f, 2.f, 4.f, 8.f, 16.f, 25.f, 36.f, 50.f, 75.f};
    int k = 0;
    float best = fabsf(fr - frs[0]);
#pragma unroll
    for (int e = 1; e < NEXP; ++e) {
        float d = fabsf(fr - frs[e]);
        if (d < best) { best = d; k = e; }
    }
    return k;
}

// ---------------- K_prep: prepack per-expert tables + zero pos ----------------
// Chunk map (chunk = 1024B = 64 lanes x 16B):
//  0      : A1 = W1^T with b1 folded at k=4 (x4=1.0), k>=5 zero
//  1..2   : A2 frags kf=0,1 — K-permuted: frag elem e,g -> row kf*16+(e&3)+8*(e>>2)+4g
//  3..6   : A3 frags (t, kf) = 3+t*2+kf — same K-permutation
//  7..10  : C2 = b2 in D layout
// 11..18  : C3 = b3 in D layout, 11+t*4+c
// 19..26  : W4D = rowsum(W4) in D layout, 19+t*4+c
// 27     : b4s = sum(b4) replicated
__global__ __launch_bounds__(64) void k_prep(const float* __restrict__ W1, const float* __restrict__ b1,
                                             const float* __restrict__ W2, const float* __restrict__ b2,
                                             const float* __restrict__ W3, const float* __restrict__ b3,
                                             const float* __restrict__ W4, const float* __restrict__ b4,
                                             char* __restrict__ tab, int* __restrict__ pos) {
    int e = blockIdx.x;
    int l = threadIdx.x;
    int g = l >> 5, m = l & 31;
    if (e == 0) {
#pragma unroll
        for (int j = 0; j < 4; ++j) pos[j * 64 + l] = 0;
    }
    char* T = tab + (size_t)e * TBL_BYTES;

    // A1
    {
        f16x8 v;
#pragma unroll
        for (int ei = 0; ei < 8; ++ei) {
            int k = g * 8 + ei;
            float w = (k < 4) ? W1[e * 128 + k * 32 + m] : (k == 4 ? b1[e * 32 + m] : 0.f);
            v[ei] = (_Float16)w;
        }
        *(f16x8*)(T + 0 * 1024 + l * 16) = v;
    }
    // A2 (K-permuted)
#pragma unroll
    for (int kf = 0; kf < 2; ++kf) {
        f16x8 v;
#pragma unroll
        for (int ei = 0; ei < 8; ++ei) {
            int row = kf * 16 + (ei & 3) + 8 * (ei >> 2) + 4 * g;
            v[ei] = (_Float16)W2[e * 1024 + row * 32 + m];
        }
        *(f16x8*)(T + (1 + kf) * 1024 + l * 16) = v;
    }
    // A3 (K-permuted)
#pragma unroll
    for (int t = 0; t < 2; ++t)
#pragma unroll
        for (int kf = 0; kf < 2; ++kf) {
            f16x8 v;
#pragma unroll
            for (int ei = 0; ei < 8; ++ei) {
                int row = kf * 16 + (ei & 3) + 8 * (ei >> 2) + 4 * g;
                v[ei] = (_Float16)W3[e * 2048 + row * 64 + t * 32 + m];
            }
            *(f16x8*)(T + (3 + t * 2 + kf) * 1024 + l * 16) = v;
        }
    // C2
#pragma unroll
    for (int c = 0; c < 4; ++c) {
        f32x4 v;
#pragma unroll
        for (int j = 0; j < 4; ++j) {
            int r = c * 4 + j;
            int row = (r & 3) + 8 * (r >> 2) + 4 * g;
            v[j] = b2[e * 32 + row];
        }
        *(f32x4*)(T + (7 + c) * 1024 + l * 16) = v;
    }
    // C3
#pragma unroll
    for (int t = 0; t < 2; ++t)
#pragma unroll
        for (int c = 0; c < 4; ++c) {
            f32x4 v;
#pragma unroll
            for (int j = 0; j < 4; ++j) {
                int r = c * 4 + j;
                int row = t * 32 + (r & 3) + 8 * (r >> 2) + 4 * g;
                v[j] = b3[e * 64 + row];
            }
            *(f32x4*)(T + (11 + t * 4 + c) * 1024 + l * 16) = v;
        }
    // W4 rowsums + b4 sum
    __shared__ float rs[64];
    {
        float s = 0.f;
        const float* w = W4 + (size_t)e * 4096 + l * 64;
        for (int o = 0; o < 64; ++o) s += w[o];
        rs[l] = s;
    }
    float bp = b4[e * 64 + l];
#pragma unroll
    for (int d = 1; d < 64; d <<= 1) bp += __shfl_xor(bp, d, 64);
    __syncthreads();
#pragma unroll
    for (int t = 0; t < 2; ++t)
#pragma unroll
        for (int c = 0; c < 4; ++c) {
            f32x4 v;
#pragma unroll
            for (int j = 0; j < 4; ++j) {
                int r = c * 4 + j;
                int row = t * 32 + (r & 3) + 8 * (r >> 2) + 4 * g;
                v[j] = rs[row];
            }
            *(f32x4*)(T + (19 + t * 4 + c) * 1024 + l * 16) = v;
        }
    f32x4 bb = {bp, bp, bp, bp};
    *(f32x4*)(T + 27 * 1024 + l * 16) = bb;
}

// ---------------- K_route: 4096 samples/block, one padded atomic per expert per block ----------------
__global__ __launch_bounds__(1024) void k_route(const float* __restrict__ feat, int n,
                                                int* __restrict__ pos,
                                                unsigned* __restrict__ idxb,
                                                uint2* __restrict__ xbuf) {
    __shared__ int wcnt[64][NEXP];       // [phase*16+wave][expert]; stride 9 -> conflict-free
    int tid = threadIdx.x;
    int wid = tid >> 6, lane = tid & 63;
    int base = blockIdx.x * RBLK;

    int kk[4];
    int rk[4];
    uint2 xw[4];

    // phase A: classify, per-wave counts, state in registers
#pragma unroll
    for (int r = 0; r < 4; ++r) {
        int i = base + r * 1024 + tid;
        int k = -1;
        uint2 w = {0u, 0u};
        if (i < n) {
            const float* f = feat + (size_t)i * 5;
            float fr = f[0];
            float x0 = f[1], x1 = f[2], x2 = f[3], x3 = f[4];
            k = expert_of(fr);
            w.x = (unsigned)pk(x0, x1);
            w.y = (unsigned)pk(x2, x3);
        }
        kk[r] = k;
        xw[r] = w;
        unsigned long long myM = 0;
#pragma unroll
        for (int e = 0; e < NEXP; ++e) {
            unsigned long long mm = __ballot(k == e);
            if (lane == 0) wcnt[r * 16 + wid][e] = __popcll(mm);
            if (k == e) myM = mm;
        }
        rk[r] = __popcll(myM & ((1ull << lane) - 1ull));
    }
    __syncthreads();

    // scan: wave w (w<9) scans expert w's 64 (phase,wave) counts; leaves absolute base
    if (wid < NEXP) {
        int e = wid;
        int v = wcnt[lane][e];
        int s = v;
#pragma unroll
        for (int d = 1; d < 64; d <<= 1) {
            int t = __shfl_up(s, d, 64);
            if (lane >= d) s += t;
        }
        int total = __shfl(s, 63, 64);
        int gbase = 0;
        if (lane == 0) gbase = atomicAdd(&pos[e * POSPAD], total);
        gbase = __shfl(gbase, 0, 64);
        wcnt[lane][e] = gbase + (s - v);   // absolute exclusive base
    }
    __syncthreads();

    // phase B: scatter from registers
#pragma unroll
    for (int r = 0; r < 4; ++r) {
        int k = kk[r];
        if (k >= 0) {
            int slot = wcnt[r * 16 + wid][k] + rk[r];
            if (slot < CAP) {
                int i = base + r * 1024 + tid;
                idxb[(size_t)k * CAP + slot] = (unsigned)i;
                xbuf[(size_t)k * CAP + slot] = xw[r];
            }
        }
    }
}

// ---------------- K_mlp: 4 tiles (128 samples) per wave, persistent fragments ----------------
__global__ __launch_bounds__(256, 3) void k_mlp(const int* __restrict__ pos,
                                                const uint2* __restrict__ xbuf,
                                                const unsigned* __restrict__ idxb,
                                                const char* __restrict__ tab,
                                                float* __restrict__ out) {
    const int bpe = CAP / 512;        // 256 blocks per expert, 512 samples each
    int e = blockIdx.x / bpe;
    int tile = blockIdx.x % bpe;
    int count = pos[e * POSPAD];
    count = count < CAP ? count : CAP;
    int base = tile * 512;
    if (base >= count) return;

    __shared__ char sm[TBL_BYTES];
    {
        const char* T = tab + (size_t)e * TBL_BYTES;
        int tid = threadIdx.x;
#pragma unroll
        for (int it = 0; it < 7; ++it) {
            int off = (it * 256 + tid) * 16;
            *(f32x4*)(sm + off) = *(const f32x4*)(T + off);
        }
    }
    __syncthreads();

    int tid = threadIdx.x;
    int wid = tid >> 6, lane = tid & 63, g = lane >> 5, m = lane & 31;
    int wbase = base + wid * 128;
    if (wbase >= count) return;       // wave-uniform; no barriers after this

    auto ldA = [&](int chunk) -> f16x8 {
        return *(const f16x8*)(sm + chunk * 1024 + lane * 16);
    };
    auto ldC = [&](int chunk) -> f32x16 {
        Q4 q;
        q.a = *(const f32x4*)(sm + (chunk + 0) * 1024 + lane * 16);
        q.b = *(const f32x4*)(sm + (chunk + 1) * 1024 + lane * 16);
        q.c = *(const f32x4*)(sm + (chunk + 2) * 1024 + lane * 16);
        q.d = *(const f32x4*)(sm + (chunk + 3) * 1024 + lane * 16);
        return __builtin_bit_cast(f32x16, q);
    };

    // persistent fragments
    f16x8 A1 = ldA(0);
    f16x8 A2a = ldA(1), A2b = ldA(2);
    f16x8 A30a = ldA(3), A30b = ldA(4), A31a = ldA(5), A31b = ldA(6);
    f32x16 C2 = ldC(7);
    f32x16 C30 = ldC(11), C31 = ldC(15);
    f32x16 W40 = ldC(19), W41 = ldC(23);
    float b4v = *(const float*)(sm + 27 * 1024);

    // sample data (4 tiles of 32)
    uint2 xt[4];
#pragma unroll
    for (int t = 0; t < 4; ++t) {
        int sl = wbase + t * 32 + m;
        bool v = sl < count;
        uint2 w = {0u, 0u};
        if (v) w = xbuf[(size_t)e * CAP + sl];
        xt[t] = w;
    }
    // store targets: g=0 stores tiles 0,1; g=1 stores tiles 2,3
    int sA = wbase + g * 64 + m;
    int sB = wbase + g * 64 + 32 + m;
    bool vA = sA < count, vB = sB < count;
    unsigned iA = vA ? idxb[(size_t)e * CAP + sA] : 0u;
    unsigned iB = vB ? idxb[(size_t)e * CAP + sB] : 0u;

    float res[4];
#pragma unroll
    for (int t = 0; t < 4; ++t) {
        // B1: g=0 lanes carry (x0,x1,x2,x3,1); g=1 half is zero K-rows
        I4 b1i = {g ? 0 : (int)xt[t].x, g ? 0 : (int)xt[t].y, g ? 0 : 0x3C00, 0};
        f16x8 B1 = __builtin_bit_cast(f16x8, b1i);

        f32x16 d1 = __builtin_amdgcn_mfma_f32_32x32x16_f16(A1, B1, zero16(), 0, 0, 0);
#pragma unroll
        for (int r = 0; r < 16; ++r) d1[r] = fmaxf(d1[r], 0.f);
        // natural packing — K-permutation is baked into A2/A3
        I4 p0 = {pk(d1[0], d1[1]), pk(d1[2], d1[3]), pk(d1[4], d1[5]), pk(d1[6], d1[7])};
        I4 p1 = {pk(d1[8], d1[9]), pk(d1[10], d1[11]), pk(d1[12], d1[13]), pk(d1[14], d1[15])};
        f16x8 B2a = __builtin_bit_cast(f16x8, p0);
        f16x8 B2b = __builtin_bit_cast(f16x8, p1);

        f32x16 d2 = __builtin_amdgcn_mfma_f32_32x32x16_f16(A2a, B2a, C2, 0, 0, 0);
        d2 = __builtin_amdgcn_mfma_f32_32x32x16_f16(A2b, B2b, d2, 0, 0, 0);
#pragma unroll
        for (int r = 0; r < 16; ++r) d2[r] = fmaxf(d2[r], 0.f);
        I4 q0 = {pk(d2[0], d2[1]), pk(d2[2], d2[3]), pk(d2[4], d2[5]), pk(d2[6], d2[7])};
        I4 q1 = {pk(d2[8], d2[9]), pk(d2[10], d2[11]), pk(d2[12], d2[13]), pk(d2[14], d2[15])};
        f16x8 B3a = __builtin_bit_cast(f16x8, q0);
        f16x8 B3b = __builtin_bit_cast(f16x8, q1);

        float acc = 0.f;
        {
            f32x16 d3 = __builtin_amdgcn_mfma_f32_32x32x16_f16(A30a, B3a, C30, 0, 0, 0);
            d3 = __builtin_amdgcn_mfma_f32_32x32x16_f16(A30b, B3b, d3, 0, 0, 0);
#pragma unroll
            for (int r = 0; r < 16; ++r) acc += fmaxf(d3[r], 0.f) * W40[r];
        }
        {
            f32x16 d3 = __builtin_amdgcn_mfma_f32_32x32x16_f16(A31a, B3a, C31, 0, 0, 0);
            d3 = __builtin_amdgcn_mfma_f32_32x32x16_f16(A31b, B3b, d3, 0, 0, 0);
#pragma unroll
            for (int r = 0; r < 16; ++r) acc += fmaxf(d3[r], 0.f) * W41[r];
        }
        acc += __shfl_xor(acc, 32, 64);
        res[t] = acc + b4v;
    }
    float rA = g ? res[2] : res[0];
    float rB = g ? res[3] : res[1];
    if (vA) out[iA] = rA;
    if (vB) out[iB] = rB;
}

// ---------------- fallback (ws too small): divergent, correct ----------------
__global__ __launch_bounds__(256) void k_fallback(const float* __restrict__ feat,
                                                  const float* __restrict__ W1, const float* __restrict__ b1,
                                                  const float* __restrict__ W2, const float* __restrict__ b2,
                                                  const float* __restrict__ W3, const float* __restrict__ b3,
                                                  const float* __restrict__ W4, const float* __restrict__ b4,
                                                  float* __restrict__ out, int n) {
    int i = blockIdx.x * 256 + threadIdx.x;
    if (i >= n) return;
    const float* f = feat + (size_t)i * 5;
    int e = expert_of(f[0]);
    float x0 = f[1], x1 = f[2], x2 = f[3], x3 = f[4];
    float h1[32], h2[32], h3[64];
    for (int j = 0; j < 32; ++j) {
        float a = b1[e * 32 + j];
        a += x0 * W1[e * 128 + 0 * 32 + j];
        a += x1 * W1[e * 128 + 1 * 32 + j];
        a += x2 * W1[e * 128 + 2 * 32 + j];
        a += x3 * W1[e * 128 + 3 * 32 + j];
        h1[j] = fmaxf(a, 0.f);
    }
    for (int j = 0; j < 32; ++j) h2[j] = b2[e * 32 + j];
    for (int i2 = 0; i2 < 32; ++i2)
        for (int j = 0; j < 32; ++j) h2[j] += h1[i2] * W2[e * 1024 + i2 * 32 + j];
    for (int j = 0; j < 32; ++j) h2[j] = fmaxf(h2[j], 0.f);
    for (int j = 0; j < 64; ++j) h3[j] = b3[e * 64 + j];
    for (int i2 = 0; i2 < 32; ++i2)
        for (int j = 0; j < 64; ++j) h3[j] += h2[i2] * W3[e * 2048 + i2 * 64 + j];
    float pred = 0.f;
    for (int o = 0; o < 64; ++o) pred += b4[e * 64 + o];
    for (int j = 0; j < 64; ++j) {
        float rsum = 0.f;
        for (int o = 0; o < 64; ++o) rsum += W4[e * 4096 + j * 64 + o];
        pred += fmaxf(h3[j], 0.f) * rsum;
    }
    out[i] = pred;
}

extern "C" void kernel_launch(void* const* d_in, const int* in_sizes, int n_in,
                              void* d_out, int out_size, void* d_ws, size_t ws_size,
                              hipStream_t stream) {
    const float* feat = (const float*)d_in[0];
    const float* W1 = (const float*)d_in[1];
    const float* b1 = (const float*)d_in[2];
    const float* W2 = (const float*)d_in[3];
    const float* b2 = (const float*)d_in[4];
    const float* W3 = (const float*)d_in[5];
    const float* b3 = (const float*)d_in[6];
    const float* W4 = (const float*)d_in[7];
    const float* b4 = (const float*)d_in[8];
    float* out = (float*)d_out;
    int n = in_sizes[0] / 5;

    const size_t off_pos = 0;                                  // 1 KB (9 counters, 64B apart)
    const size_t off_tab = 1024;                               // 9 * 28 KB
    const size_t off_x = off_tab + (size_t)NEXP * TBL_BYTES;   // 9 * CAP * 8 B
    const size_t off_idx = off_x + (size_t)NEXP * CAP * 8;     // 9 * CAP * 4 B
    const size_t need = off_idx + (size_t)NEXP * CAP * 4;

    if (ws_size >= need && n <= CAP * NEXP) {
        char* ws = (char*)d_ws;
        int* pos = (int*)(ws + off_pos);
        char* tab = ws + off_tab;
        uint2* xbuf = (uint2*)(ws + off_x);
        unsigned* idxb = (unsigned*)(ws + off_idx);

        k_prep<<<NEXP, 64, 0, stream>>>(W1, b1, W2, b2, W3, b3, W4, b4, tab, pos);
        k_route<<<(n + RBLK - 1) / RBLK, 1024, 0, stream>>>(feat, n, pos, idxb, xbuf);
        k_mlp<<<NEXP * (CAP / 512), 256, 0, stream>>>(pos, xbuf, idxb, tab, out);
    } else {
        k_fallback<<<(n + 255) / 256, 256, 0, stream>>>(feat, W1, b1, W2, b2, W3, b3, W4, b4, out, n);
    }
}